// Round 12
// baseline (3370.834 us; speedup 1.0000x reference)
//
#include <hip/hip_runtime.h>

typedef unsigned short u16;
typedef unsigned int u32;
typedef unsigned long long u64;
typedef __attribute__((ext_vector_type(8))) short bf16x8;   // 8 bf16 in 4 VGPRs
typedef __attribute__((ext_vector_type(4))) float f32x4;

#define T_ 512
#define B_ 64
#define IN_ 128
#define H_ 512
#define C_ 32
#define BH_ (B_ * H_)        // 32768 elems per h plane
#define NWG_CELL 192         // 3 layers x 64 (each WG owns 32u x 16b)
#define NWG_TOT 196          // + 4 out-proj WGs

// ---- flag indices (x32 u32 stride = 128B line separation) ----
// R7-VERIFIED protocol (frozen — R8/R9 lesson: plain-store publish races):
// acnt[L][mb]  : arrive counter (atomic fetch_add)
// gen[L][mb]   : == t+1 when ALL 16 ug-WGs finished step t (last arriver)
// rack/rgen[Lm][mb][s] : same min-gate pattern for input-stage acks
// fo[mb][s]    : outproj ack counter (single writer -> exact count)
#define FA(L, mb)       ((((L) * 4 + (mb))) * 32)
#define FG(L, mb)       (((12 + (L) * 4 + (mb))) * 32)
#define FRA(Lm, mb, s)  (((24 + ((Lm) * 4 + (mb)) * 3 + (s))) * 32)
#define FRG(Lm, mb, s)  (((48 + ((Lm) * 4 + (mb)) * 3 + (s))) * 32)
#define FO(mb, s)       (((72 + (mb) * 3 + (s))) * 32)
#define NFLAG 84

#define DEVINL __device__ __attribute__((always_inline)) inline

// ---------- bf16 split helpers (RNE) ----------
DEVINL u16 f2bf_(float f) {
    u32 u = __float_as_uint(f);
    u32 r = (u + 0x7FFFu + ((u >> 16) & 1u)) >> 16;
    return (u16)r;
}
DEVINL float bf2f_(u16 h) { return __uint_as_float(((u32)h) << 16); }

// ---------- LLC-direct (agent-scope, relaxed) ops ----------
DEVINL u64 ld_llc_u64(const u64* p) {
    return __hip_atomic_load((u64*)p, __ATOMIC_RELAXED, __HIP_MEMORY_SCOPE_AGENT);
}
DEVINL void st_llc_u32(u32* p, u32 v) {
    __hip_atomic_store(p, v, __ATOMIC_RELAXED, __HIP_MEMORY_SCOPE_AGENT);
}
DEVINL u32 ld_flag(const u32* p) {
    return __hip_atomic_load((u32*)p, __ATOMIC_RELAXED, __HIP_MEMORY_SCOPE_AGENT);
}
DEVINL u32 add_flag(u32* p) {
    return __hip_atomic_fetch_add(p, 1u, __ATOMIC_RELAXED, __HIP_MEMORY_SCOPE_AGENT);
}
DEVINL void st_flag(u32* p, u32 v) {
    __hip_atomic_store(p, v, __ATOMIC_RELAXED, __HIP_MEMORY_SCOPE_AGENT);
}
DEVINL void wait_ge(u32* p, u32 v) {
    while (ld_flag(p) < v) __builtin_amdgcn_s_sleep(1);
}

// ---------- weight / h0 split kernel: fp32 -> (hi, lo) bf16 planes ----------
__global__ void split_kernel(const float* __restrict__ src, u16* __restrict__ hi,
                             u16* __restrict__ lo, int n) {
    int i = blockIdx.x * 256 + threadIdx.x;
    if (i < n) {
        float f = src[i];
        u16 h = f2bf_(f);
        hi[i] = h;
        lo[i] = f2bf_(f - bf2f_(h));
    }
}

// ---------- params ----------
struct Params {
    const float* x;
    const u16* ih_hi[3]; const u16* ih_lo[3];
    const u16* hh_hi[3]; const u16* hh_lo[3];
    const float* b_ih[3]; const float* b_hh[3];
    const u16* wout_hi; const u16* wout_lo;
    const float* b_out;
    u16* h_hi; u16* h_lo;   // [3 layers][3 slots][B*H]; h(t) in slot t%3, h0 in slot 2
    u32* bar;               // flag counters (zeroed per launch)
    float* y;               // [B][T][C]
};

// ---------- MFMA helpers ----------
DEVINL bf16x8 ld8(const u16* p) { return *reinterpret_cast<const bf16x8*>(p); }

// staged-h LDS read: [16][512] u16 rows, byte ^= (row&7)<<4 swizzle
DEVINL bf16x8 ld8_lds(const u16* s, int row, int kb) {
    const int bo = (row << 10) + (((kb) << 1) ^ ((row & 7) << 4));
    return *reinterpret_cast<const bf16x8*>((const char*)s + bo);
}

DEVINL f32x4 mfma3(bf16x8 ah, bf16x8 al, bf16x8 bh, bf16x8 bl, f32x4 c) {
    c = __builtin_amdgcn_mfma_f32_16x16x32_bf16(ah, bh, c, 0, 0, 0);
    c = __builtin_amdgcn_mfma_f32_16x16x32_bf16(al, bh, c, 0, 0, 0);
    c = __builtin_amdgcn_mfma_f32_16x16x32_bf16(ah, bl, c, 0, 0, 0);
    return c;
}

DEVINL void gemm3_reg(const u16* sAh, const u16* sAl, int row,
                      const bf16x8 (&w)[3][2][16], int lhi,
                      f32x4& o0, f32x4& o1, f32x4& o2) {
    f32x4 a0 = {0.f,0.f,0.f,0.f}, a1 = {0.f,0.f,0.f,0.f}, a2 = {0.f,0.f,0.f,0.f};
#pragma unroll
    for (int kt = 0; kt < 16; ++kt) {
        const int kb = kt * 32 + lhi * 8;
        bf16x8 ah = ld8_lds(sAh, row, kb), al = ld8_lds(sAl, row, kb);
        a0 = mfma3(ah, al, w[0][0][kt], w[0][1][kt], a0);
        a1 = mfma3(ah, al, w[1][0][kt], w[1][1][kt], a1);
        a2 = mfma3(ah, al, w[2][0][kt], w[2][1][kt], a2);
    }
    o0 = a0; o1 = a1; o2 = a2;
}

DEVINL void gemm2_reg(const u16* sAh, const u16* sAl, int row,
                      const bf16x8 (&w)[3][2][16], int lhi,
                      f32x4& o0, f32x4& o1) {
    f32x4 a0 = {0.f,0.f,0.f,0.f}, a1 = {0.f,0.f,0.f,0.f};
#pragma unroll
    for (int kt = 0; kt < 16; ++kt) {
        const int kb = kt * 32 + lhi * 8;
        bf16x8 ah = ld8_lds(sAh, row, kb), al = ld8_lds(sAl, row, kb);
        a0 = mfma3(ah, al, w[0][0][kt], w[0][1][kt], a0);
        a1 = mfma3(ah, al, w[1][0][kt], w[1][1][kt], a1);
    }
    o0 = a0; o1 = a1;
}

// ---------- stage one h block (16 rows x 512, hi+lo) LLC->LDS ----------
DEVINL void stage_h(const u16* ghi, const u16* glo,
                    u16* shi, u16* slo, int b0, int tid) {
#pragma unroll
    for (int c = 0; c < 2; ++c) {
        u64 rh[4], rl[4];
#pragma unroll
        for (int k = 0; k < 4; ++k) {
            const int idx = tid + ((c * 4 + k) << 8);
            const int row = idx >> 7, col = idx & 127;   // 128 u64 per 512-u16 row
            rh[k] = ld_llc_u64((const u64*)(ghi + (size_t)(b0 + row) * H_) + col);
            rl[k] = ld_llc_u64((const u64*)(glo + (size_t)(b0 + row) * H_) + col);
        }
#pragma unroll
        for (int k = 0; k < 4; ++k) {
            const int idx = tid + ((c * 4 + k) << 8);
            const int row = idx >> 7;
            const int so = (row << 10) + (((idx & 127) << 3) ^ ((row & 7) << 4));
            *(u64*)((char*)shi + so) = rh[k];
            *(u64*)((char*)slo + so) = rl[k];
        }
    }
}

// C/D layout (m89-verified): col = lane&15, row = (lane>>4)*4 + reg
DEVINL void store_sg(float (&dst)[16][33], f32x4 a, int col, int lhi) {
#pragma unroll
    for (int q = 0; q < 4; ++q) dst[lhi * 4 + q][col] = a[q];
}

// ---------- persistent kernel: R10 protocol (frozen) + cycle shortening ----------
// R12 changes (publish mechanics byte-identical to R7/R10):
//  - TAIL-PREFETCH: layer L stages input h_{L-1}(t+1) at the TAIL of step t
//    (gated on gen[L-1] >= t+2). Step head then gates only {own, WAR} and
//    stages only the own block (1 LLC RT on the recurrence cycle, not 2).
//    Input-ack moves to the next step's head, after barrier #0 (whose vmcnt
//    drain certifies ALL threads' tail loads) — same round formula, same
//    semantics ("slot copied to LDS"), just earlier in wall time.
//    Deadlock-free: L-1 can run exactly 3 ahead on already-given acks
//    (3-slot buffer), so gen[L-1] >= t+2 is always eventually satisfied.
//  - PUBLISHER SPLIT: tid 64 (wave 1) issues the publish after barrier #3
//    while tid 0 concurrently starts the tail gate poll — publish RT hides
//    under the tail stage instead of serializing before the next gate.
__global__ __launch_bounds__(256, 1) void gru_pipe(Params p) {
    __shared__ u16 hs[4][8192];          // [own_hi, own_lo, in_hi, in_lo], 64KB
    __shared__ float sg[6][16][33];
    __shared__ float slog[16][33];
    const int wg = blockIdx.x, tid = threadIdx.x;
    const int wave = tid >> 6, lane = tid & 63;
    const int ln15 = lane & 15, lhi = lane >> 4;
    u32* F = p.bar;

    // ---- prologue: pin this wave's weight tiles in registers (VGPR+AGPR) ----
    bf16x8 wreg[3][2][16];
    const int L = (wg < NWG_CELL) ? (wg >> 6) : 0;
    const int wgl = wg & 63, ug = wgl & 15, mb = wgl >> 4;
    const int u0 = ug * 32, b0c = mb * 16;
    const int tt0 = wave * 3;
    if (wg < NWG_CELL) {
        if (wave >= 2) {
#pragma unroll
            for (int j = 0; j < 3; ++j) {
                const int tt = tt0 + j, g = (tt >> 1) - 3, c = (tt & 1) * 16 + ln15;
                const u16* bh = p.hh_hi[L] + (size_t)(g * H_ + u0 + c) * H_;
                const u16* bl = p.hh_lo[L] + (size_t)(g * H_ + u0 + c) * H_;
#pragma unroll
                for (int kt = 0; kt < 16; ++kt) {
                    wreg[j][0][kt] = ld8(bh + kt * 32 + lhi * 8);
                    wreg[j][1][kt] = ld8(bl + kt * 32 + lhi * 8);
                }
            }
        } else if (L > 0) {
#pragma unroll
            for (int j = 0; j < 3; ++j) {
                const int tt = tt0 + j, g = tt >> 1, c = (tt & 1) * 16 + ln15;
                const u16* bh = p.ih_hi[L] + (size_t)(g * H_ + u0 + c) * H_;
                const u16* bl = p.ih_lo[L] + (size_t)(g * H_ + u0 + c) * H_;
#pragma unroll
                for (int kt = 0; kt < 16; ++kt) {
                    wreg[j][0][kt] = ld8(bh + kt * 32 + lhi * 8);
                    wreg[j][1][kt] = ld8(bl + kt * 32 + lhi * 8);
                }
            }
        } else {
#pragma unroll
            for (int j = 0; j < 3; ++j) {
                const int tt = tt0 + j, g = tt >> 1, c = (tt & 1) * 16 + ln15;
                const u16* bh = p.ih_hi[0] + (size_t)(g * H_ + u0 + c) * IN_;
                const u16* bl = p.ih_lo[0] + (size_t)(g * H_ + u0 + c) * IN_;
#pragma unroll
                for (int kt = 0; kt < 4; ++kt) {
                    wreg[j][0][kt] = ld8(bh + kt * 32 + lhi * 8);
                    wreg[j][1][kt] = ld8(bl + kt * 32 + lhi * 8);
                }
            }
        }
    } else if (wave == 0) {
#pragma unroll
        for (int j = 0; j < 2; ++j) {
            const u16* bh = p.wout_hi + (size_t)(j * 16 + ln15) * H_;
            const u16* bl = p.wout_lo + (size_t)(j * 16 + ln15) * H_;
#pragma unroll
            for (int kt = 0; kt < 16; ++kt) {
                wreg[j][0][kt] = ld8(bh + kt * 32 + lhi * 8);
                wreg[j][1][kt] = ld8(bl + kt * 32 + lhi * 8);
            }
        }
    }

    if (wg < NWG_CELL) {
        // ---- pre-loop: stage input h_{L-1}(0) (slot 0) for step 0 ----
        if (L > 0) {
            if (tid == 0) wait_ge(&F[FG(L - 1, mb)], 1u);
            __syncthreads();
            stage_h(p.h_hi + (size_t)(3 * (L - 1)) * BH_,
                    p.h_lo + (size_t)(3 * (L - 1)) * BH_, hs[2], hs[3], b0c, tid);
            // ack deferred to step 0's head (after barrier #0)
        }
        for (int t = 0; t < T_; ++t) {
            const int sCur = t % 3, sPrev = (t + 2) % 3;

            // ---- L0: prefetch x(t) into registers (no gate dependency) ----
            float xq[32];
            if (L == 0 && wave < 2) {
                const float* xr = p.x + (size_t)(b0c + ln15) * (T_ * IN_) + (size_t)t * IN_;
#pragma unroll
                for (int kt = 0; kt < 4; ++kt)
#pragma unroll
                    for (int j = 0; j < 8; ++j)
                        xq[kt * 8 + j] = xr[kt * 32 + lhi * 8 + j];
            }

            // ---- head gate: own + WAR only (input handled at tail) ----
            if (tid == 0) {
                u32* gO = &F[FG(L, mb)];
                const u32 thrO = (u32)t;
                u32* gW = gO; u32 thrW = 0u;
                if (t >= 3) {
                    thrW = (u32)((t - 3) / 3) + 1u;
                    gW = (L < 2) ? &F[FRG(L, mb, sCur)] : &F[FO(mb, sCur)];
                }
                while ((u32)(ld_flag(gO) < thrO) | (u32)(ld_flag(gW) < thrW)) {
                    __builtin_amdgcn_s_sleep(1);
                }
            }
            __syncthreads();                                 // #0 (drains x + tail loads)
            if (tid == 0 && L > 0) {     // ack input slot sCur (staged last tail/pre-loop)
                const u32 k = (u32)(t / 3) + 1u;
                u32 old = add_flag(&F[FRA(L - 1, mb, sCur)]);
                if (old == 16u * k - 1u) st_flag(&F[FRG(L - 1, mb, sCur)], k);
            }

            // ---- own-block stage only (1 LLC RT on the cycle) ----
            stage_h(p.h_hi + (size_t)(3 * L + sPrev) * BH_,
                    p.h_lo + (size_t)(3 * L + sPrev) * BH_, hs[0], hs[1], b0c, tid);
            __syncthreads();                                 // #1: stage visible WG-wide

            f32x4 oA, oB, oC;
            if (wave < 2 && L == 0) {
                // A = x_t from prefetched registers; split on the fly; K = 128
                f32x4 a0 = {0.f,0.f,0.f,0.f}, a1 = {0.f,0.f,0.f,0.f}, a2 = {0.f,0.f,0.f,0.f};
#pragma unroll
                for (int kt = 0; kt < 4; ++kt) {
                    bf16x8 ah, al;
#pragma unroll
                    for (int j = 0; j < 8; ++j) {
                        float f = xq[kt * 8 + j];
                        u16 hb = f2bf_(f);
                        ah[j] = (short)hb;
                        al[j] = (short)f2bf_(f - bf2f_(hb));
                    }
                    a0 = mfma3(ah, al, wreg[0][0][kt], wreg[0][1][kt], a0);
                    a1 = mfma3(ah, al, wreg[1][0][kt], wreg[1][1][kt], a1);
                    a2 = mfma3(ah, al, wreg[2][0][kt], wreg[2][1][kt], a2);
                }
                oA = a0; oB = a1; oC = a2;
            } else {
                const u16* sAh = (wave < 2) ? hs[2] : hs[0];
                const u16* sAl = (wave < 2) ? hs[3] : hs[1];
                gemm3_reg(sAh, sAl, ln15, wreg, lhi, oA, oB, oC);
            }
            {
                const int gA = (tt0    ) >> 1, cA = ((tt0    ) & 1) * 16 + ln15;
                const int gB = (tt0 + 1) >> 1, cB = ((tt0 + 1) & 1) * 16 + ln15;
                const int gC = (tt0 + 2) >> 1, cC = ((tt0 + 2) & 1) * 16 + ln15;
                store_sg(sg[gA], oA, cA, lhi);
                store_sg(sg[gB], oB, cB, lhi);
                store_sg(sg[gC], oC, cC, lhi);
            }
            __syncthreads();                                 // #2: sg visible WG-wide

            // ---- elementwise GRU update (fp32): 2 consecutive u per thread ----
            {
                const int rb = tid & 15, uu = tid >> 4;
                const int colu = uu * 2;
                const int gcol = u0 + colu;
                const u32 hp2h = *(const u32*)((const char*)hs[0] + (rb << 10) + ((gcol * 2) ^ ((rb & 7) << 4)));
                const u32 hp2l = *(const u32*)((const char*)hs[1] + (rb << 10) + ((gcol * 2) ^ ((rb & 7) << 4)));
                u32 packh = 0, packl = 0;
#pragma unroll
                for (int half = 0; half < 2; ++half) {
                    const int uc = colu + half;
                    const int uidx = u0 + uc;
                    const float ir  = sg[0][rb][uc] + p.b_ih[L][uidx];
                    const float iz  = sg[1][rb][uc] + p.b_ih[L][H_ + uidx];
                    const float in_ = sg[2][rb][uc] + p.b_ih[L][2 * H_ + uidx];
                    const float hr  = sg[3][rb][uc] + p.b_hh[L][uidx];
                    const float hz  = sg[4][rb][uc] + p.b_hh[L][H_ + uidx];
                    const float hn  = sg[5][rb][uc] + p.b_hh[L][2 * H_ + uidx];
                    const float r = 1.f / (1.f + expf(-(ir + hr)));
                    const float z = 1.f / (1.f + expf(-(iz + hz)));
                    const float n = tanhf(in_ + r * hn);
                    const float hprev = bf2f_((u16)((half ? (hp2h >> 16) : hp2h) & 0xffffu))
                                      + bf2f_((u16)((half ? (hp2l >> 16) : hp2l) & 0xffffu));
                    const float hnew = (1.f - z) * n + z * hprev;
                    const u16 nh = f2bf_(hnew);
                    const u16 nl = f2bf_(hnew - bf2f_(nh));
                    packh |= (u32)nh << (16 * half);
                    packl |= (u32)nl << (16 * half);
                }
                u16* ho_hi = p.h_hi + (size_t)(3 * L + sCur) * BH_;
                u16* ho_lo = p.h_lo + (size_t)(3 * L + sCur) * BH_;
                const size_t hx = (size_t)(b0c + rb) * H_ + gcol;
                st_llc_u32((u32*)(ho_hi + hx), packh);      // write-through to LLC
                st_llc_u32((u32*)(ho_lo + hx), packl);
            }
            __syncthreads();                                 // #3: drains vmcnt (h stores done)
            if (tid == 64) {                                 // publish h(t) — PUBLISHER SPLIT
                u32 old = add_flag(&F[FA(L, mb)]);
                if (old == 16u * (u32)(t + 1) - 1u) st_flag(&F[FG(L, mb)], (u32)(t + 1));
            }
            // ---- tail: prefetch input h_{L-1}(t+1) (overlaps our publish RT) ----
            if (L > 0 && t + 1 < T_) {
                if (tid == 0) wait_ge(&F[FG(L - 1, mb)], (u32)(t + 2));
                __syncthreads();                             // #4: tail gate -> WG
                const int sNext = (t + 1) % 3;
                stage_h(p.h_hi + (size_t)(3 * (L - 1) + sNext) * BH_,
                        p.h_lo + (size_t)(3 * (L - 1) + sNext) * BH_, hs[2], hs[3], b0c, tid);
                // loads certified by next step's barrier #0; ack at next head
            }
        }
    } else {
        const int mbo = wg - NWG_CELL, b0 = mbo * 16;
        for (int t = 0; t < T_; ++t) {
            const int s = t % 3;
            if (tid == 0) wait_ge(&F[FG(2, mbo)], (u32)(t + 1));   // h3(t) done (min-gate)
            __syncthreads();
            stage_h(p.h_hi + (size_t)(6 + s) * BH_, p.h_lo + (size_t)(6 + s) * BH_,
                    hs[0], hs[1], b0, tid);
            __syncthreads();
            if (tid == 0) add_flag(&F[FO(mbo, s)]);          // ack h3(t) stage (exact count)
            if (wave == 0) {
                f32x4 a0, a1;
                gemm2_reg(hs[0], hs[1], ln15, wreg, lhi, a0, a1);
#pragma unroll
                for (int q = 0; q < 4; ++q) {
                    slog[lhi * 4 + q][ln15] = a0[q];
                    slog[lhi * 4 + q][16 + ln15] = a1[q];
                }
            }
            __syncthreads();
            if (tid < 16) {
                float v[32];
                float m = -1e30f;
#pragma unroll
                for (int c = 0; c < 32; ++c) { v[c] = slog[tid][c] + p.b_out[c]; m = fmaxf(m, v[c]); }
                float sden = 0.f;
#pragma unroll
                for (int c = 0; c < 32; ++c) { v[c] = expf(v[c] - m); sden += v[c]; }
                const float inv = 1.f / sden;
                float* yp = p.y + ((size_t)(b0 + tid) * T_ + t) * C_;
#pragma unroll
                for (int c = 0; c < 32; ++c) yp[c] = v[c] * inv;
            }
        }
    }
}

extern "C" void kernel_launch(void* const* d_in, const int* in_sizes, int n_in,
                              void* d_out, int out_size, void* d_ws, size_t ws_size,
                              hipStream_t stream) {
    (void)in_sizes; (void)n_in; (void)out_size; (void)ws_size;

    const float* x      = (const float*)d_in[0];
    const float* h0[3]  = {(const float*)d_in[1], (const float*)d_in[2], (const float*)d_in[3]};
    const float* Wih[3] = {(const float*)d_in[4], (const float*)d_in[8], (const float*)d_in[12]};
    const float* Whh[3] = {(const float*)d_in[5], (const float*)d_in[9], (const float*)d_in[13]};
    const float* bih[3] = {(const float*)d_in[6], (const float*)d_in[10], (const float*)d_in[14]};
    const float* bhh[3] = {(const float*)d_in[7], (const float*)d_in[11], (const float*)d_in[15]};
    const float* Wout   = (const float*)d_in[16];
    const float* bout   = (const float*)d_in[17];

    // ---- ws layout (u16 units): split-bf16 weights + 3-slot h state + flags ----
    u16* w = (u16*)d_ws;
    size_t off = 0;
    auto take = [&](size_t n) { u16* p = w + off; off += n; return p; };
    u16 *ihh[3], *ihl[3], *hhh[3], *hhl[3];
    const size_t szih[3] = {(size_t)3 * H_ * IN_, (size_t)3 * H_ * H_, (size_t)3 * H_ * H_};
    const size_t szhh = (size_t)3 * H_ * H_;
    for (int l = 0; l < 3; ++l) {
        ihh[l] = take(szih[l]); ihl[l] = take(szih[l]);
        hhh[l] = take(szhh);    hhl[l] = take(szhh);
    }
    u16* wouth = take((size_t)C_ * H_);
    u16* woutl = take((size_t)C_ * H_);
    u16* hhi = take((size_t)3 * 3 * BH_);
    u16* hlo = take((size_t)3 * 3 * BH_);
    off = (off + 255) & ~(size_t)255;               // align flags to 512B
    u32* bar = (u32*)take(2 * (NFLAG * 32));        // NFLAG*32 u32 words
    const size_t bar_bytes = (size_t)NFLAG * 32 * sizeof(u32);

    hipMemsetAsync(bar, 0, bar_bytes, stream);      // reset flags every launch (graph-safe)

    auto split = [&](const float* src, u16* hi, u16* lo, int n) {
        split_kernel<<<dim3((n + 255) / 256), dim3(256), 0, stream>>>(src, hi, lo, n);
    };
    for (int l = 0; l < 3; ++l) {
        split(Wih[l], ihh[l], ihl[l], (int)szih[l]);
        split(Whh[l], hhh[l], hhl[l], (int)szhh);
    }
    split(Wout, wouth, woutl, C_ * H_);
    for (int l = 0; l < 3; ++l)   // h0 = version -1 -> slot 2 of each layer
        split(h0[l], hhi + (size_t)(3 * l + 2) * BH_, hlo + (size_t)(3 * l + 2) * BH_, BH_);

    Params p;
    p.x = x;
    for (int l = 0; l < 3; ++l) {
        p.ih_hi[l] = ihh[l]; p.ih_lo[l] = ihl[l];
        p.hh_hi[l] = hhh[l]; p.hh_lo[l] = hhl[l];
        p.b_ih[l] = bih[l];  p.b_hh[l] = bhh[l];
    }
    p.wout_hi = wouth; p.wout_lo = woutl; p.b_out = bout;
    p.h_hi = hhi; p.h_lo = hlo;
    p.bar = bar;
    p.y = (float*)d_out;

    void* args[] = {&p};
    hipError_t err = hipLaunchCooperativeKernel((void*)gru_pipe, dim3(NWG_TOT), dim3(256),
                                                args, 0u, stream);
    if (err != hipSuccess) {
        // flags-only sync needs co-residency, not cooperative semantics;
        // 196 blocks trivially co-reside on 256 CUs.
        gru_pipe<<<dim3(NWG_TOT), dim3(256), 0, stream>>>(p);
    }
}

// Round 13
// 3029.521 us; speedup vs baseline: 1.1127x; 1.1127x over previous
//
#include <hip/hip_runtime.h>

typedef unsigned short u16;
typedef unsigned int u32;
typedef unsigned long long u64;
typedef __attribute__((ext_vector_type(8))) short bf16x8;   // 8 bf16 in 4 VGPRs
typedef __attribute__((ext_vector_type(4))) float f32x4;

#define T_ 512
#define B_ 64
#define IN_ 128
#define H_ 512
#define C_ 32
#define BH_ (B_ * H_)        // 32768 elems per h plane
#define NWG_CELL 192         // 3 layers x 64 (each WG owns 32u x 16b)
#define NWG_TOT 196          // + 4 out-proj WGs

// ---- flag indices (x32 u32 stride = 128B line separation) ----
// R7-VERIFIED protocol (frozen — R8/R9 lesson: plain-store publish races):
// acnt[L][mb]  : arrive counter (atomic fetch_add)
// gen[L][mb]   : == t+1 when ALL 16 ug-WGs finished step t (last arriver)
// rack/rgen[Lm][mb][s] : same min-gate pattern for input-stage acks
// fo[mb][s]    : outproj ack counter (single writer -> exact count)
#define FA(L, mb)       ((((L) * 4 + (mb))) * 32)
#define FG(L, mb)       (((12 + (L) * 4 + (mb))) * 32)
#define FRA(Lm, mb, s)  (((24 + ((Lm) * 4 + (mb)) * 3 + (s))) * 32)
#define FRG(Lm, mb, s)  (((48 + ((Lm) * 4 + (mb)) * 3 + (s))) * 32)
#define FO(mb, s)       (((72 + (mb) * 3 + (s))) * 32)
#define NFLAG 84

#define DEVINL __device__ __attribute__((always_inline)) inline

// ---------- bf16 split helpers (RNE) ----------
DEVINL u16 f2bf_(float f) {
    u32 u = __float_as_uint(f);
    u32 r = (u + 0x7FFFu + ((u >> 16) & 1u)) >> 16;
    return (u16)r;
}
DEVINL float bf2f_(u16 h) { return __uint_as_float(((u32)h) << 16); }

// ---------- LLC-direct (agent-scope, relaxed) ops ----------
DEVINL u64 ld_llc_u64(const u64* p) {
    return __hip_atomic_load((u64*)p, __ATOMIC_RELAXED, __HIP_MEMORY_SCOPE_AGENT);
}
DEVINL void st_llc_u32(u32* p, u32 v) {
    __hip_atomic_store(p, v, __ATOMIC_RELAXED, __HIP_MEMORY_SCOPE_AGENT);
}
DEVINL u32 ld_flag(const u32* p) {
    return __hip_atomic_load((u32*)p, __ATOMIC_RELAXED, __HIP_MEMORY_SCOPE_AGENT);
}
DEVINL u32 add_flag(u32* p) {
    return __hip_atomic_fetch_add(p, 1u, __ATOMIC_RELAXED, __HIP_MEMORY_SCOPE_AGENT);
}
DEVINL void st_flag(u32* p, u32 v) {
    __hip_atomic_store(p, v, __ATOMIC_RELAXED, __HIP_MEMORY_SCOPE_AGENT);
}
DEVINL void wait_ge(u32* p, u32 v) {
    while (ld_flag(p) < v) __builtin_amdgcn_s_sleep(1);
}

// ---------- weight / h0 split kernel: fp32 -> (hi, lo) bf16 planes ----------
__global__ void split_kernel(const float* __restrict__ src, u16* __restrict__ hi,
                             u16* __restrict__ lo, int n) {
    int i = blockIdx.x * 256 + threadIdx.x;
    if (i < n) {
        float f = src[i];
        u16 h = f2bf_(f);
        hi[i] = h;
        lo[i] = f2bf_(f - bf2f_(h));
    }
}

// ---------- params ----------
struct Params {
    const float* x;
    const u16* ih_hi[3]; const u16* ih_lo[3];
    const u16* hh_hi[3]; const u16* hh_lo[3];
    const float* b_ih[3]; const float* b_hh[3];
    const u16* wout_hi; const u16* wout_lo;
    const float* b_out;
    u16* h_hi; u16* h_lo;   // [3 layers][3 slots][B*H]; h(t) in slot t%3, h0 in slot 2
    u32* bar;               // flag counters (zeroed per launch)
    float* y;               // [B][T][C]
};

// ---------- MFMA helpers ----------
DEVINL bf16x8 ld8(const u16* p) { return *reinterpret_cast<const bf16x8*>(p); }

// staged-h LDS read: [16][512] u16 rows, byte ^= (row&7)<<4 swizzle
DEVINL bf16x8 ld8_lds(const u16* s, int row, int kb) {
    const int bo = (row << 10) + (((kb) << 1) ^ ((row & 7) << 4));
    return *reinterpret_cast<const bf16x8*>((const char*)s + bo);
}

DEVINL f32x4 mfma3(bf16x8 ah, bf16x8 al, bf16x8 bh, bf16x8 bl, f32x4 c) {
    c = __builtin_amdgcn_mfma_f32_16x16x32_bf16(ah, bh, c, 0, 0, 0);
    c = __builtin_amdgcn_mfma_f32_16x16x32_bf16(al, bh, c, 0, 0, 0);
    c = __builtin_amdgcn_mfma_f32_16x16x32_bf16(ah, bl, c, 0, 0, 0);
    return c;
}

DEVINL void gemm3_reg(const u16* sAh, const u16* sAl, int row,
                      const bf16x8 (&w)[3][2][16], int lhi,
                      f32x4& o0, f32x4& o1, f32x4& o2) {
    f32x4 a0 = {0.f,0.f,0.f,0.f}, a1 = {0.f,0.f,0.f,0.f}, a2 = {0.f,0.f,0.f,0.f};
#pragma unroll
    for (int kt = 0; kt < 16; ++kt) {
        const int kb = kt * 32 + lhi * 8;
        bf16x8 ah = ld8_lds(sAh, row, kb), al = ld8_lds(sAl, row, kb);
        a0 = mfma3(ah, al, w[0][0][kt], w[0][1][kt], a0);
        a1 = mfma3(ah, al, w[1][0][kt], w[1][1][kt], a1);
        a2 = mfma3(ah, al, w[2][0][kt], w[2][1][kt], a2);
    }
    o0 = a0; o1 = a1; o2 = a2;
}

DEVINL void gemm2_reg(const u16* sAh, const u16* sAl, int row,
                      const bf16x8 (&w)[3][2][16], int lhi,
                      f32x4& o0, f32x4& o1) {
    f32x4 a0 = {0.f,0.f,0.f,0.f}, a1 = {0.f,0.f,0.f,0.f};
#pragma unroll
    for (int kt = 0; kt < 16; ++kt) {
        const int kb = kt * 32 + lhi * 8;
        bf16x8 ah = ld8_lds(sAh, row, kb), al = ld8_lds(sAl, row, kb);
        a0 = mfma3(ah, al, w[0][0][kt], w[0][1][kt], a0);
        a1 = mfma3(ah, al, w[1][0][kt], w[1][1][kt], a1);
    }
    o0 = a0; o1 = a1;
}

// ---------- stage one h block (16 rows x 512, hi+lo) LLC->LDS ----------
DEVINL void stage_h(const u16* ghi, const u16* glo,
                    u16* shi, u16* slo, int b0, int tid) {
#pragma unroll
    for (int c = 0; c < 2; ++c) {
        u64 rh[4], rl[4];
#pragma unroll
        for (int k = 0; k < 4; ++k) {
            const int idx = tid + ((c * 4 + k) << 8);
            const int row = idx >> 7, col = idx & 127;   // 128 u64 per 512-u16 row
            rh[k] = ld_llc_u64((const u64*)(ghi + (size_t)(b0 + row) * H_) + col);
            rl[k] = ld_llc_u64((const u64*)(glo + (size_t)(b0 + row) * H_) + col);
        }
#pragma unroll
        for (int k = 0; k < 4; ++k) {
            const int idx = tid + ((c * 4 + k) << 8);
            const int row = idx >> 7;
            const int so = (row << 10) + (((idx & 127) << 3) ^ ((row & 7) << 4));
            *(u64*)((char*)shi + so) = rh[k];
            *(u64*)((char*)slo + so) = rl[k];
        }
    }
}

// C/D layout (m89-verified): col = lane&15, row = (lane>>4)*4 + reg
DEVINL void store_sg(float (&dst)[16][33], f32x4 a, int col, int lhi) {
#pragma unroll
    for (int q = 0; q < 4; ++q) dst[lhi * 4 + q][col] = a[q];
}

// ---------- persistent kernel: R7-protocol, fused single-poll gate ----------
// R13 = exact revert to R10 (best verified: 3.03 ms, absmax 4.88e-4).
// Campaign record: R11 (x-prefetch, fused stage) flat; R12 (tail-prefetch,
// publisher split) regressed −10%. R8/R9 (plain-store publish) failed with
// HW-level visibility races. The step cost is the structural sync cycle:
// stage RT + GEMM + drain + RMW-publish + observe + 16-way convoy ≈ 6 µs.
__global__ __launch_bounds__(256, 1) void gru_pipe(Params p) {
    __shared__ u16 hs[4][8192];          // [own_hi, own_lo, in_hi, in_lo], 64KB
    __shared__ float sg[6][16][33];
    __shared__ float slog[16][33];
    const int wg = blockIdx.x, tid = threadIdx.x;
    const int wave = tid >> 6, lane = tid & 63;
    const int ln15 = lane & 15, lhi = lane >> 4;
    u32* F = p.bar;

    // ---- prologue: pin this wave's weight tiles in registers (VGPR+AGPR) ----
    bf16x8 wreg[3][2][16];
    const int L = (wg < NWG_CELL) ? (wg >> 6) : 0;
    const int wgl = wg & 63, ug = wgl & 15, mb = wgl >> 4;
    const int u0 = ug * 32, b0c = mb * 16;
    const int tt0 = wave * 3;
    if (wg < NWG_CELL) {
        if (wave >= 2) {
#pragma unroll
            for (int j = 0; j < 3; ++j) {
                const int tt = tt0 + j, g = (tt >> 1) - 3, c = (tt & 1) * 16 + ln15;
                const u16* bh = p.hh_hi[L] + (size_t)(g * H_ + u0 + c) * H_;
                const u16* bl = p.hh_lo[L] + (size_t)(g * H_ + u0 + c) * H_;
#pragma unroll
                for (int kt = 0; kt < 16; ++kt) {
                    wreg[j][0][kt] = ld8(bh + kt * 32 + lhi * 8);
                    wreg[j][1][kt] = ld8(bl + kt * 32 + lhi * 8);
                }
            }
        } else if (L > 0) {
#pragma unroll
            for (int j = 0; j < 3; ++j) {
                const int tt = tt0 + j, g = tt >> 1, c = (tt & 1) * 16 + ln15;
                const u16* bh = p.ih_hi[L] + (size_t)(g * H_ + u0 + c) * H_;
                const u16* bl = p.ih_lo[L] + (size_t)(g * H_ + u0 + c) * H_;
#pragma unroll
                for (int kt = 0; kt < 16; ++kt) {
                    wreg[j][0][kt] = ld8(bh + kt * 32 + lhi * 8);
                    wreg[j][1][kt] = ld8(bl + kt * 32 + lhi * 8);
                }
            }
        } else {
#pragma unroll
            for (int j = 0; j < 3; ++j) {
                const int tt = tt0 + j, g = tt >> 1, c = (tt & 1) * 16 + ln15;
                const u16* bh = p.ih_hi[0] + (size_t)(g * H_ + u0 + c) * IN_;
                const u16* bl = p.ih_lo[0] + (size_t)(g * H_ + u0 + c) * IN_;
#pragma unroll
                for (int kt = 0; kt < 4; ++kt) {
                    wreg[j][0][kt] = ld8(bh + kt * 32 + lhi * 8);
                    wreg[j][1][kt] = ld8(bl + kt * 32 + lhi * 8);
                }
            }
        }
    } else if (wave == 0) {
#pragma unroll
        for (int j = 0; j < 2; ++j) {
            const u16* bh = p.wout_hi + (size_t)(j * 16 + ln15) * H_;
            const u16* bl = p.wout_lo + (size_t)(j * 16 + ln15) * H_;
#pragma unroll
            for (int kt = 0; kt < 16; ++kt) {
                wreg[j][0][kt] = ld8(bh + kt * 32 + lhi * 8);
                wreg[j][1][kt] = ld8(bl + kt * 32 + lhi * 8);
            }
        }
    }

    if (wg < NWG_CELL) {
        for (int t = 0; t < T_; ++t) {
            const int sCur = t % 3, sPrev = (t + 2) % 3;
            // ---- FUSED gate: own + input + WAR in ONE poll loop (tid0) ----
            if (tid == 0) {
                u32* gO = &F[FG(L, mb)];
                const u32 thrO = (u32)t;
                u32* gI = (L > 0) ? &F[FG(L - 1, mb)] : gO;
                const u32 thrI = (L > 0) ? (u32)(t + 1) : 0u;
                u32* gW = gO; u32 thrW = 0u;
                if (t >= 3) {
                    thrW = (u32)((t - 3) / 3) + 1u;
                    gW = (L < 2) ? &F[FRG(L, mb, sCur)] : &F[FO(mb, sCur)];
                }
                // bitwise | : all three loads issue per iteration (no short-circuit)
                while ((u32)(ld_flag(gO) < thrO) | (u32)(ld_flag(gI) < thrI) |
                       (u32)(ld_flag(gW) < thrW)) {
                    __builtin_amdgcn_s_sleep(1);
                }
            }
            __syncthreads();                                 // #0: gate -> WG

            stage_h(p.h_hi + (size_t)(3 * L + sPrev) * BH_,
                    p.h_lo + (size_t)(3 * L + sPrev) * BH_, hs[0], hs[1], b0c, tid);
            if (L > 0)
                stage_h(p.h_hi + (size_t)(3 * (L - 1) + sCur) * BH_,
                        p.h_lo + (size_t)(3 * (L - 1) + sCur) * BH_, hs[2], hs[3], b0c, tid);
            __syncthreads();                                 // #1: stage visible WG-wide
            if (tid == 0 && L > 0) {                 // ack input stage (min-gate publish)
                const u32 k = (u32)(t / 3) + 1u;
                u32 old = add_flag(&F[FRA(L - 1, mb, sCur)]);
                if (old == 16u * k - 1u) st_flag(&F[FRG(L - 1, mb, sCur)], k);
            }

            f32x4 oA, oB, oC;
            if (wave < 2 && L == 0) {
                // A = x_t rows (cached loads), split on the fly; K = 128
                const float* xr = p.x + (size_t)(b0c + ln15) * (T_ * IN_) + (size_t)t * IN_;
                f32x4 a0 = {0.f,0.f,0.f,0.f}, a1 = {0.f,0.f,0.f,0.f}, a2 = {0.f,0.f,0.f,0.f};
#pragma unroll
                for (int kt = 0; kt < 4; ++kt) {
                    const int kb = kt * 32 + lhi * 8;
                    bf16x8 ah, al;
#pragma unroll
                    for (int j = 0; j < 8; ++j) {
                        float f = xr[kb + j];
                        u16 hb = f2bf_(f);
                        ah[j] = (short)hb;
                        al[j] = (short)f2bf_(f - bf2f_(hb));
                    }
                    a0 = mfma3(ah, al, wreg[0][0][kt], wreg[0][1][kt], a0);
                    a1 = mfma3(ah, al, wreg[1][0][kt], wreg[1][1][kt], a1);
                    a2 = mfma3(ah, al, wreg[2][0][kt], wreg[2][1][kt], a2);
                }
                oA = a0; oB = a1; oC = a2;
            } else {
                const u16* sAh = (wave < 2) ? hs[2] : hs[0];
                const u16* sAl = (wave < 2) ? hs[3] : hs[1];
                gemm3_reg(sAh, sAl, ln15, wreg, lhi, oA, oB, oC);
            }
            {
                const int gA = (tt0    ) >> 1, cA = ((tt0    ) & 1) * 16 + ln15;
                const int gB = (tt0 + 1) >> 1, cB = ((tt0 + 1) & 1) * 16 + ln15;
                const int gC = (tt0 + 2) >> 1, cC = ((tt0 + 2) & 1) * 16 + ln15;
                store_sg(sg[gA], oA, cA, lhi);
                store_sg(sg[gB], oB, cB, lhi);
                store_sg(sg[gC], oC, cC, lhi);
            }
            __syncthreads();                                 // #2: sg visible WG-wide

            // ---- elementwise GRU update (fp32): 2 consecutive u per thread ----
            {
                const int rb = tid & 15, uu = tid >> 4;
                const int colu = uu * 2;
                const int gcol = u0 + colu;
                const u32 hp2h = *(const u32*)((const char*)hs[0] + (rb << 10) + ((gcol * 2) ^ ((rb & 7) << 4)));
                const u32 hp2l = *(const u32*)((const char*)hs[1] + (rb << 10) + ((gcol * 2) ^ ((rb & 7) << 4)));
                u32 packh = 0, packl = 0;
#pragma unroll
                for (int half = 0; half < 2; ++half) {
                    const int uc = colu + half;
                    const int uidx = u0 + uc;
                    const float ir  = sg[0][rb][uc] + p.b_ih[L][uidx];
                    const float iz  = sg[1][rb][uc] + p.b_ih[L][H_ + uidx];
                    const float in_ = sg[2][rb][uc] + p.b_ih[L][2 * H_ + uidx];
                    const float hr  = sg[3][rb][uc] + p.b_hh[L][uidx];
                    const float hz  = sg[4][rb][uc] + p.b_hh[L][H_ + uidx];
                    const float hn  = sg[5][rb][uc] + p.b_hh[L][2 * H_ + uidx];
                    const float r = 1.f / (1.f + expf(-(ir + hr)));
                    const float z = 1.f / (1.f + expf(-(iz + hz)));
                    const float n = tanhf(in_ + r * hn);
                    const float hprev = bf2f_((u16)((half ? (hp2h >> 16) : hp2h) & 0xffffu))
                                      + bf2f_((u16)((half ? (hp2l >> 16) : hp2l) & 0xffffu));
                    const float hnew = (1.f - z) * n + z * hprev;
                    const u16 nh = f2bf_(hnew);
                    const u16 nl = f2bf_(hnew - bf2f_(nh));
                    packh |= (u32)nh << (16 * half);
                    packl |= (u32)nl << (16 * half);
                }
                u16* ho_hi = p.h_hi + (size_t)(3 * L + sCur) * BH_;
                u16* ho_lo = p.h_lo + (size_t)(3 * L + sCur) * BH_;
                const size_t hx = (size_t)(b0c + rb) * H_ + gcol;
                st_llc_u32((u32*)(ho_hi + hx), packh);      // write-through to LLC
                st_llc_u32((u32*)(ho_lo + hx), packl);
            }
            __syncthreads();                                 // #3: drains vmcnt (h stores done)
            if (tid == 0) {                                  // publish h(t) (min-gate, R7 exact)
                u32 old = add_flag(&F[FA(L, mb)]);
                if (old == 16u * (u32)(t + 1) - 1u) st_flag(&F[FG(L, mb)], (u32)(t + 1));
            }
        }
    } else {
        const int mbo = wg - NWG_CELL, b0 = mbo * 16;
        for (int t = 0; t < T_; ++t) {
            const int s = t % 3;
            if (tid == 0) wait_ge(&F[FG(2, mbo)], (u32)(t + 1));   // h3(t) done (min-gate)
            __syncthreads();
            stage_h(p.h_hi + (size_t)(6 + s) * BH_, p.h_lo + (size_t)(6 + s) * BH_,
                    hs[0], hs[1], b0, tid);
            __syncthreads();
            if (tid == 0) add_flag(&F[FO(mbo, s)]);          // ack h3(t) stage (exact count)
            if (wave == 0) {
                f32x4 a0, a1;
                gemm2_reg(hs[0], hs[1], ln15, wreg, lhi, a0, a1);
#pragma unroll
                for (int q = 0; q < 4; ++q) {
                    slog[lhi * 4 + q][ln15] = a0[q];
                    slog[lhi * 4 + q][16 + ln15] = a1[q];
                }
            }
            __syncthreads();
            if (tid < 16) {
                float v[32];
                float m = -1e30f;
#pragma unroll
                for (int c = 0; c < 32; ++c) { v[c] = slog[tid][c] + p.b_out[c]; m = fmaxf(m, v[c]); }
                float sden = 0.f;
#pragma unroll
                for (int c = 0; c < 32; ++c) { v[c] = expf(v[c] - m); sden += v[c]; }
                const float inv = 1.f / sden;
                float* yp = p.y + ((size_t)(b0 + tid) * T_ + t) * C_;
#pragma unroll
                for (int c = 0; c < 32; ++c) yp[c] = v[c] * inv;
            }
        }
    }
}

extern "C" void kernel_launch(void* const* d_in, const int* in_sizes, int n_in,
                              void* d_out, int out_size, void* d_ws, size_t ws_size,
                              hipStream_t stream) {
    (void)in_sizes; (void)n_in; (void)out_size; (void)ws_size;

    const float* x      = (const float*)d_in[0];
    const float* h0[3]  = {(const float*)d_in[1], (const float*)d_in[2], (const float*)d_in[3]};
    const float* Wih[3] = {(const float*)d_in[4], (const float*)d_in[8], (const float*)d_in[12]};
    const float* Whh[3] = {(const float*)d_in[5], (const float*)d_in[9], (const float*)d_in[13]};
    const float* bih[3] = {(const float*)d_in[6], (const float*)d_in[10], (const float*)d_in[14]};
    const float* bhh[3] = {(const float*)d_in[7], (const float*)d_in[11], (const float*)d_in[15]};
    const float* Wout   = (const float*)d_in[16];
    const float* bout   = (const float*)d_in[17];

    // ---- ws layout (u16 units): split-bf16 weights + 3-slot h state + flags ----
    u16* w = (u16*)d_ws;
    size_t off = 0;
    auto take = [&](size_t n) { u16* p = w + off; off += n; return p; };
    u16 *ihh[3], *ihl[3], *hhh[3], *hhl[3];
    const size_t szih[3] = {(size_t)3 * H_ * IN_, (size_t)3 * H_ * H_, (size_t)3 * H_ * H_};
    const size_t szhh = (size_t)3 * H_ * H_;
    for (int l = 0; l < 3; ++l) {
        ihh[l] = take(szih[l]); ihl[l] = take(szih[l]);
        hhh[l] = take(szhh);    hhl[l] = take(szhh);
    }
    u16* wouth = take((size_t)C_ * H_);
    u16* woutl = take((size_t)C_ * H_);
    u16* hhi = take((size_t)3 * 3 * BH_);
    u16* hlo = take((size_t)3 * 3 * BH_);
    off = (off + 255) & ~(size_t)255;               // align flags to 512B
    u32* bar = (u32*)take(2 * (NFLAG * 32));        // NFLAG*32 u32 words
    const size_t bar_bytes = (size_t)NFLAG * 32 * sizeof(u32);

    hipMemsetAsync(bar, 0, bar_bytes, stream);      // reset flags every launch (graph-safe)

    auto split = [&](const float* src, u16* hi, u16* lo, int n) {
        split_kernel<<<dim3((n + 255) / 256), dim3(256), 0, stream>>>(src, hi, lo, n);
    };
    for (int l = 0; l < 3; ++l) {
        split(Wih[l], ihh[l], ihl[l], (int)szih[l]);
        split(Whh[l], hhh[l], hhl[l], (int)szhh);
    }
    split(Wout, wouth, woutl, C_ * H_);
    for (int l = 0; l < 3; ++l)   // h0 = version -1 -> slot 2 of each layer
        split(h0[l], hhi + (size_t)(3 * l + 2) * BH_, hlo + (size_t)(3 * l + 2) * BH_, BH_);

    Params p;
    p.x = x;
    for (int l = 0; l < 3; ++l) {
        p.ih_hi[l] = ihh[l]; p.ih_lo[l] = ihl[l];
        p.hh_hi[l] = hhh[l]; p.hh_lo[l] = hhl[l];
        p.b_ih[l] = bih[l];  p.b_hh[l] = bhh[l];
    }
    p.wout_hi = wouth; p.wout_lo = woutl; p.b_out = bout;
    p.h_hi = hhi; p.h_lo = hlo;
    p.bar = bar;
    p.y = (float*)d_out;

    void* args[] = {&p};
    hipError_t err = hipLaunchCooperativeKernel((void*)gru_pipe, dim3(NWG_TOT), dim3(256),
                                                args, 0u, stream);
    if (err != hipSuccess) {
        // flags-only sync needs co-residency, not cooperative semantics;
        // 196 blocks trivially co-reside on 256 CUs.
        gru_pipe<<<dim3(NWG_TOT), dim3(256), 0, stream>>>(p);
    }
}